// Round 10
// baseline (1688.072 us; speedup 1.0000x reference)
//
#include <hip/hip_runtime.h>
#include <hip/hip_bf16.h>
#include <math.h>

#define BB 64      // batch
#define CC 64      // width/channels
#define SS 8192    // sequence
#define HS 4096    // SS/2 (radix-2 half)
#define NMODE 256  // kept rfft modes
#define KK2 512    // 2*NMODE (re/im interleaved, permuted [even-k | odd-k])

typedef __attribute__((ext_vector_type(8))) short short8;
typedef __attribute__((ext_vector_type(16))) float f32x16;

#define VMW6 asm volatile("s_waitcnt vmcnt(6)" ::: "memory")
#define VMW4 asm volatile("s_waitcnt vmcnt(4)" ::: "memory")
#define VMW0 asm volatile("s_waitcnt vmcnt(0)" ::: "memory")
#define SBAR asm volatile("s_barrier" ::: "memory")

__device__ __forceinline__ float gelu_exact(float v) {
    return 0.5f * v * (1.0f + erff(v * 0.7071067811865476f));
}
__device__ __forceinline__ float b2f(ushort u) {
    return __uint_as_float(((unsigned int)u) << 16);
}
__device__ __forceinline__ ushort f2b(float v) {
    __hip_bfloat16 h = __float2bfloat16(v);  // RNE
    return *(ushort*)&h;
}
__device__ __forceinline__ void split2(float v, ushort& h, ushort& l) {
    h = f2b(v);
    l = f2b(v - b2f(h));
}
// permuted col -> true frequency k
__device__ __forceinline__ int colk(int c) {
    return (c < 256) ? (c & ~1) : (((c - 256) & ~1) | 1);
}
// async global->LDS DMA, 16B per lane; dest = wave-uniform base + lane*16
__device__ __forceinline__ void dma16(const ushort* g, ushort* l) {
    __builtin_amdgcn_global_load_lds((const __attribute__((address_space(1))) void*)g,
                                     (__attribute__((address_space(3))) void*)l, 16, 0, 0);
}

// ---------------- DFT basis tables (bf16 hi/lo pairs, permuted cols) --------
// T1p[c][n<4096]: forward table (even-k rows pair with E, odd-k with O).
// T2r[n<4096][c]: inverse table. value = ri ? -sin(2πkn/S) : cos(2πkn/S).
__global__ void build_T1p(ushort* __restrict__ h, ushort* __restrict__ l) {
    int c = blockIdx.x;
    int n = blockIdx.y * 256 + threadIdx.x;
    int k = colk(c), ri = c & 1;
    int m = (n * k) & (SS - 1);
    float th = (float)m * (6.283185307179586476925f / (float)SS);
    float s, co;
    sincosf(th, &s, &co);
    float v = ri ? -s : co;
    ushort hh, ll;
    split2(v, hh, ll);
    h[(size_t)c * HS + n] = hh;
    l[(size_t)c * HS + n] = ll;
}

__global__ void build_T2r(ushort* __restrict__ h, ushort* __restrict__ l) {
    int n = blockIdx.x;
    int c = blockIdx.y * 256 + threadIdx.x;
    int k = colk(c), ri = c & 1;
    int m = (n * k) & (SS - 1);
    float th = (float)m * (6.283185307179586476925f / (float)SS);
    float s, co;
    sincosf(th, &s, &co);
    float v = ri ? -s : co;
    ushort hh, ll;
    split2(v, hh, ll);
    h[(size_t)n * KK2 + c] = hh;
    l[(size_t)n * KK2 + c] = ll;
}

__global__ void zero_xf(float* __restrict__ p) {
    size_t i = ((size_t)blockIdx.x * 256 + threadIdx.x) * 4;
    *(float4*)&p[i] = make_float4(0.f, 0.f, 0.f, 0.f);
}

// ---------------- lifting layer (writes split E/O directly) ----------------
__global__ void lift_kernel(const float* __restrict__ u, const float* __restrict__ w0,
                            const float* __restrict__ b0, ushort* __restrict__ Eh,
                            ushort* __restrict__ El, ushort* __restrict__ Oh,
                            ushort* __restrict__ Ol) {
    int n = blockIdx.x * 256 + threadIdx.x;  // 0..4095
    int c = blockIdx.y;
    int b = blockIdx.z;
    float g1 = (float)n * (1.0f / (float)(SS - 1));
    float g2 = (float)(n + HS) * (1.0f / (float)(SS - 1));
    float v1 = u[b * SS + n] * w0[c] + g1 * w0[CC + c] + b0[c];
    float v2 = u[b * SS + n + HS] * w0[c] + g2 * w0[CC + c] + b0[c];
    float E = v1 + v2, O = v1 - v2;
    ushort hh, ll;
    size_t idx = (size_t)(b * CC + c) * HS + n;
    split2(E, hh, ll);
    Eh[idx] = hh;
    El[idx] = ll;
    split2(O, hh, ll);
    Oh[idx] = hh;
    Ol[idx] = ll;
}

// ---------------- forward truncated DFT (radix-2): K=4096 MFMA GEMM --------
// v3: occupancy release. Round-9 analysis: 152 regs/wave (88V + 64A acc)
// allows 3 waves/SIMD but launch_bounds(256,2) + grid 512 (2 blk/CU) capped
// it. Now 8 k-splits (grid 1024 = 4 blk/CU, 3 resident), K-step 16, dbuf
// 2x16KB = 32 KB (3x32 <= 160 OK), launch_bounds(256,3). Wave w stages
// array w (Ah/Al/Bh/Bl), 4 dma16/wave, counted vmcnt(4).
__global__ __launch_bounds__(256, 3) void dft_mfma(
    const ushort* __restrict__ Eh, const ushort* __restrict__ El,
    const ushort* __restrict__ Oh, const ushort* __restrict__ Ol,
    const ushort* __restrict__ t1h, const ushort* __restrict__ t1l,
    float* __restrict__ Xf) {
    __shared__ __align__(16) ushort SM[16384];  // 32 KB: two 16 KB buffers
    const int t = threadIdx.x;
    const int L = blockIdx.x;  // 1024 blocks
    const int gq = L >> 5, j = L & 31;
    const int c0 = (j >> 3) * 128;
    const int m0 = ((gq & 3) * 8 + (j & 7)) * 128;
    const int kz = (gq >> 2) * 512;  // 8 k-splits over K=4096
    const ushort* __restrict__ Ahp = (c0 < 256) ? Eh : Oh;
    const ushort* __restrict__ Alp = (c0 < 256) ? El : Ol;
    const int lane = t & 63, w = t >> 6;
    const int wm = (w >> 1) * 64, wn = (w & 1) * 64;
    const int l32 = lane & 31, lh = lane >> 5;

    f32x16 acc[2][2];
#pragma unroll
    for (int i = 0; i < 2; i++)
#pragma unroll
        for (int jj = 0; jj < 2; jj++) acc[i][jj] = (f32x16)0.f;

    // wave w stages array w into region w*2048: [kg2][128 rows][8]
    const ushort* const srcw = (w == 0) ? Ahp : (w == 1) ? Alp : (w == 2) ? t1h : t1l;
    const int rbase = (w < 2) ? m0 : c0;
    const size_t soff = (size_t)(rbase + lane) * HS;
    const size_t r64 = (size_t)64 * HS;

    auto stage = [&](int kt, int bsel) {
        ushort* dst = SM + bsel * 8192 + w * 2048;
        dma16(srcw + soff + kt, dst);                   // kg0, rows 0..63
        dma16(srcw + soff + r64 + kt, dst + 512);       // kg0, rows 64..127
        dma16(srcw + soff + kt + 8, dst + 1024);        // kg1, rows 0..63
        dma16(srcw + soff + r64 + kt + 8, dst + 1536);  // kg1, rows 64..127
    };
    auto compute = [&](int bsel) {
        const ushort* base = SM + bsel * 8192;
        const int kg = lh;
        short8 ah[2], al[2], bh2[2], bl2[2];
#pragma unroll
        for (int mt = 0; mt < 2; mt++) {
            int off = (kg * 128 + wm + mt * 32 + l32) * 8;
            ah[mt] = *(const short8*)&base[off];
            al[mt] = *(const short8*)&base[2048 + off];
        }
#pragma unroll
        for (int nt = 0; nt < 2; nt++) {
            int off = (kg * 128 + wn + nt * 32 + l32) * 8;
            bh2[nt] = *(const short8*)&base[4096 + off];
            bl2[nt] = *(const short8*)&base[6144 + off];
        }
#pragma unroll
        for (int nt = 0; nt < 2; nt++)
#pragma unroll
            for (int mt = 0; mt < 2; mt++) {
                acc[mt][nt] = __builtin_amdgcn_mfma_f32_32x32x16_bf16(ah[mt], bh2[nt], acc[mt][nt], 0, 0, 0);
                acc[mt][nt] = __builtin_amdgcn_mfma_f32_32x32x16_bf16(ah[mt], bl2[nt], acc[mt][nt], 0, 0, 0);
                acc[mt][nt] = __builtin_amdgcn_mfma_f32_32x32x16_bf16(al[mt], bh2[nt], acc[mt][nt], 0, 0, 0);
            }
    };

    stage(kz, 0);
#pragma unroll 1
    for (int st = 0; st < 32; st++) {  // 32 K=16 steps over this split's K=512
        const int buf = st & 1;
        if (st < 31) {
            stage(kz + (st + 1) * 16, buf ^ 1);
            VMW4;  // wait only for step st's 4 DMAs; st+1's stay in flight
        } else {
            VMW0;
        }
        SBAR;
        compute(buf);
        SBAR;
    }
#pragma unroll
    for (int mt = 0; mt < 2; mt++)
#pragma unroll
        for (int nt = 0; nt < 2; nt++) {
            int col = c0 + wn + nt * 32 + l32;
#pragma unroll
            for (int reg = 0; reg < 16; reg++) {
                int row = m0 + wm + mt * 32 + (reg & 3) + 8 * (reg >> 2) + 4 * lh;
                atomicAdd(&Xf[(size_t)row * KK2 + col], acc[mt][nt][reg]);
            }
        }
}

// ---------------- mode mixing (permuted cols) --------------------------------
__global__ __launch_bounds__(256) void mode_mix(const float* __restrict__ Xf,
                                                const float* __restrict__ swr,
                                                const float* __restrict__ swi,
                                                ushort* __restrict__ omh,
                                                ushort* __restrict__ oml, int l) {
    int k = threadIdx.x;
    int bg = blockIdx.x * 2;
    int og = blockIdx.y * 2;
    const int cp = ((k & 1) << 8) | ((k >> 1) << 1);  // permuted re-col
    float ar[2][2] = {}, ai[2][2] = {};
#pragma unroll 2
    for (int i = 0; i < CC; i++) {
        float2 x0 = *(const float2*)&Xf[((size_t)(bg + 0) * CC + i) * KK2 + cp];
        float2 x1 = *(const float2*)&Xf[((size_t)(bg + 1) * CC + i) * KK2 + cp];
        size_t wb = ((size_t)(l * CC + i) * CC + og) * NMODE + k;
        float wr0 = swr[wb], wi0 = swi[wb];
        float wr1 = swr[wb + NMODE], wi1 = swi[wb + NMODE];
        ar[0][0] += x0.x * wr0 - x0.y * wi0;
        ai[0][0] += x0.x * wi0 + x0.y * wr0;
        ar[0][1] += x0.x * wr1 - x0.y * wi1;
        ai[0][1] += x0.x * wi1 + x0.y * wr1;
        ar[1][0] += x1.x * wr0 - x1.y * wi0;
        ai[1][0] += x1.x * wi0 + x1.y * wr0;
        ar[1][1] += x1.x * wr1 - x1.y * wi1;
        ai[1][1] += x1.x * wi1 + x1.y * wr1;
    }
    float ck = (k == 0) ? (1.0f / (float)SS) : (2.0f / (float)SS);
#pragma unroll
    for (int b2 = 0; b2 < 2; b2++)
#pragma unroll
        for (int oo = 0; oo < 2; oo++) {
            float re = ar[b2][oo] * ck;
            float im = ai[b2][oo] * ck;
            ushort hr, lr2, hi2, li2;
            split2(re, hr, lr2);
            split2(im, hi2, li2);
            size_t base = ((size_t)(bg + b2) * CC + og + oo) * KK2 + cp;
            *(ushort2*)&omh[base] = make_ushort2(hr, hi2);
            *(ushort2*)&oml[base] = make_ushort2(lr2, li2);
        }
}

// ---------------- inverse DFT (radix-2) + pointwise + gelu -------------------
// v5: occupancy via smaller wave tile, VERIFIED reg budget (round-6 lesson:
// budget first). Block = 128 rows x 64 n, 4 waves (2x2), wave tile 64x32 ->
// acc = aP[2]+aQ[2] = 64 AGPR (was 128). Phase-2 peak: 64 pw-frag VGPR +
// ~36 temps + 64 AGPR ~= 164 <= 512/3 = 170 -> 3 waves/SIMD. LDS 2x24KB =
// 48 KB (3x48 <= 160). Butterfly stays register-local (each wave holds both
// P and Q). Counted vmcnt (6 phase-1 / 4 phase-2), raw s_barrier, phase-2
// round 0 prefetched during phase-1 step 15.
__global__ __launch_bounds__(256, 3) void inv_mfma(
    const ushort* __restrict__ omh, const ushort* __restrict__ oml,
    const ushort* __restrict__ t2h, const ushort* __restrict__ t2l,
    const float* __restrict__ pww, const float* __restrict__ pwb,
    ushort* __restrict__ Eh, ushort* __restrict__ El,
    ushort* __restrict__ Oh, ushort* __restrict__ Ol, int l, int gel) {
    __shared__ __align__(16) ushort SM[24576];  // 48 KB: two 24 KB buffers
    const int t = threadIdx.x;
    const int n0 = blockIdx.x * 64;    // n < 4096
    const int row0 = blockIdx.y * 128; // 2 batches x 64 out-ch
    const int lane = t & 63, w = t >> 6;
    const int wm = (w >> 1) * 64, wn = (w & 1) * 32;
    const int l32 = lane & 31, lh = lane >> 5;

    f32x16 aP[2], aQ[2];
    aP[0] = (f32x16)0.f;
    aP[1] = (f32x16)0.f;
    aQ[0] = (f32x16)0.f;
    aQ[1] = (f32x16)0.f;

    // buffer layout (ushorts): Ah[kg4][128][8] @0 (4096), Al @4096,
    // Bh[kg4][64][8] @8192 (2048), Bl @10240. Buffer stride 12288.
    // staging roles: sel = w>>1 (0=hi, 1=lo arrays), p = w&1 (kg pair)
    const int sel = w >> 1, p = w & 1;
    const ushort* const Asrc = sel ? oml : omh;
    const ushort* const Bsrc = sel ? t2l : t2h;
    const size_t aoff = (size_t)(row0 + lane) * KK2;
    const size_t boff = (size_t)(n0 + lane) * KK2;
    const size_t r64 = (size_t)64 * KK2;

    auto stage1 = [&](int st, int bsel) {
        const int kt = st * 32 + 2 * p * 8;
        ushort* dA = SM + bsel * 12288 + sel * 4096 + 2 * p * 1024;
        ushort* dB = SM + bsel * 12288 + 8192 + sel * 2048 + 2 * p * 512;
        dma16(Asrc + aoff + kt, dA);              // kg=2p,   rows 0..63
        dma16(Asrc + aoff + r64 + kt, dA + 512);  // kg=2p,   rows 64..127
        dma16(Asrc + aoff + kt + 8, dA + 1024);   // kg=2p+1, rows 0..63
        dma16(Asrc + aoff + r64 + kt + 8, dA + 1536);
        dma16(Bsrc + boff + kt, dB);              // kg=2p   (64 n-rows)
        dma16(Bsrc + boff + kt + 8, dB + 512);    // kg=2p+1
    };
    // phase-2: x tile [bs2][ch64][n64] = 16 KB at buffer base. Wave w stages
    // bs = w>>1, ch-half = (w&1)*32; chunk q covers 8 ch x 64 n.
    const size_t xsrc = (size_t)(row0 + (w >> 1) * 64 + (w & 1) * 32 + (lane >> 3)) * HS +
                        n0 + (lane & 7) * 8;
    auto stage2 = [&](const ushort* src, int bsel) {
        ushort* dX = SM + bsel * 12288 + (w >> 1) * 4096 + (w & 1) * 2048;
#pragma unroll
        for (int q = 0; q < 4; q++) dma16(src + xsrc + (size_t)q * 8 * HS, dX + q * 512);
    };
    auto compute1 = [&](f32x16* acc, const int bsel) {
        const ushort* base = SM + bsel * 12288;
#pragma unroll
        for (int s2 = 0; s2 < 2; s2++) {
            const int kg = s2 * 2 + lh;
            short8 ah[2], al[2];
#pragma unroll
            for (int mt = 0; mt < 2; mt++) {
                int off = (kg * 128 + wm + mt * 32 + l32) * 8;
                ah[mt] = *(const short8*)&base[off];
                al[mt] = *(const short8*)&base[4096 + off];
            }
            const int offb = (kg * 64 + wn + l32) * 8;
            short8 bh = *(const short8*)&base[8192 + offb];
            short8 bl = *(const short8*)&base[10240 + offb];
#pragma unroll
            for (int mt = 0; mt < 2; mt++) {
                acc[mt] = __builtin_amdgcn_mfma_f32_32x32x16_bf16(ah[mt], bh, acc[mt], 0, 0, 0);
                acc[mt] = __builtin_amdgcn_mfma_f32_32x32x16_bf16(ah[mt], bl, acc[mt], 0, 0, 0);
                acc[mt] = __builtin_amdgcn_mfma_f32_32x32x16_bf16(al[mt], bh, acc[mt], 0, 0, 0);
            }
        }
    };

    // ---- phase 1: P (steps 0..7, even-k cols 0..255), Q (steps 8..15) ----
    stage1(0, 0);
#pragma unroll 1
    for (int st = 0; st < 8; st++) {
        const int buf = st & 1;
        stage1(st + 1, buf ^ 1);
        VMW6;
        SBAR;
        compute1(aP, buf);
        SBAR;
    }
#pragma unroll 1
    for (int st = 8; st < 15; st++) {
        const int buf = st & 1;
        stage1(st + 1, buf ^ 1);
        VMW6;
        SBAR;
        compute1(aQ, buf);
        SBAR;
    }
    {  // st = 15 (buf 1): prefetch phase-2 round 0 (Eh tile) into buf 0.
       // outstanding = step15's 6 + stage2's 4; VMW4 drains exactly step15's.
        stage2(Eh, 0);
        VMW4;
        SBAR;
        compute1(aQ, 1);
        SBAR;
    }
    // butterfly (register-local): aP := u = P+Q (y[n]), aQ := v = P-Q
#pragma unroll
    for (int mt = 0; mt < 2; mt++) {
        f32x16 pp2 = aP[mt];
        aP[mt] = pp2 + aQ[mt];
        aQ[mt] = pp2 - aQ[mt];
    }
    // hoisted pw fragments (pw/2, bf16 hi/lo); channel index = mt*32 + l32
    short8 pah[4][2], pal[4][2];
#pragma unroll
    for (int ks = 0; ks < 4; ks++)
#pragma unroll
        for (int mt = 0; mt < 2; mt++) {
            const float* pp = &pww[(size_t)(l * CC + mt * 32 + l32) * CC + ks * 16 + lh * 8];
            float4 pa = *(const float4*)pp;
            float4 pb = *(const float4*)(pp + 4);
            float pv[8] = {pa.x, pa.y, pa.z, pa.w, pb.x, pb.y, pb.z, pb.w};
#pragma unroll
            for (int e = 0; e < 8; e++) {
                ushort h2, l2;
                split2(0.5f * pv[e], h2, l2);
                pah[ks][mt][e] = (short)h2;
                pal[ks][mt][e] = (short)l2;
            }
        }
    // ---- phase 2: pointwise, 4 chained rounds (Eh, El, Oh, Ol), dbuf'd ----
    const int bsw = w >> 1;
    const ushort* const srcs[4] = {Eh, El, Oh, Ol};
#pragma unroll
    for (int r = 0; r < 4; r++) {
        const int buf = r & 1;
        const bool isO = (r >= 2), isHi = !(r & 1);
        if (r < 3) {
            stage2(srcs[r + 1], buf ^ 1);
            VMW4;
        } else {
            VMW0;
        }
        SBAR;
        const ushort* base = SM + buf * 12288;
#pragma unroll
        for (int ks = 0; ks < 4; ks++) {
            short8 bf, nbf;
            const int rb = (bsw * 64 + ks * 16 + lh * 8) * 64 + wn + l32;
#pragma unroll
            for (int jj = 0; jj < 8; jj++) bf[jj] = (short)base[rb + jj * 64];
            if (isO) {
#pragma unroll
                for (int jj = 0; jj < 8; jj++) nbf[jj] = (short)(bf[jj] ^ (short)0x8000);
            }
#pragma unroll
            for (int mt = 0; mt < 2; mt++) {
                aP[mt] = __builtin_amdgcn_mfma_f32_32x32x16_bf16(pah[ks][mt], bf, aP[mt], 0, 0, 0);
                aQ[mt] = __builtin_amdgcn_mfma_f32_32x32x16_bf16(pah[ks][mt], isO ? nbf : bf, aQ[mt], 0, 0, 0);
                if (isHi) {
                    aP[mt] = __builtin_amdgcn_mfma_f32_32x32x16_bf16(pal[ks][mt], bf, aP[mt], 0, 0, 0);
                    aQ[mt] = __builtin_amdgcn_mfma_f32_32x32x16_bf16(pal[ks][mt], isO ? nbf : bf, aQ[mt], 0, 0, 0);
                }
            }
        }
        if (r < 3) SBAR;  // readers done before next round's DMA overwrites buf
    }
    // epilogue: bias + gelu on both halves, butterfly to E/O, split-store
#pragma unroll
    for (int mt = 0; mt < 2; mt++)
#pragma unroll
        for (int reg = 0; reg < 16; reg++) {
            int roffs = (reg & 3) + 8 * (reg >> 2) + 4 * lh;
            float bias = pwb[l * CC + mt * 32 + roffs];
            float uu = aP[mt][reg] + bias;
            float vv = aQ[mt][reg] + bias;
            if (gel) {
                uu = gelu_exact(uu);
                vv = gelu_exact(vv);
            }
            float EE = uu + vv, OO = uu - vv;
            ushort h2, l2;
            size_t gg = (size_t)(row0 + wm + mt * 32 + roffs) * HS + n0 + wn + l32;
            split2(EE, h2, l2);
            Eh[gg] = h2;
            El[gg] = l2;
            split2(OO, h2, l2);
            Oh[gg] = h2;
            Ol[gg] = l2;
        }
}

// ---------------- projection head (MFMA, register-transpose staging) --------
// Block: one (b, 64-position) tile. Fragment assembly happens in REGISTERS
// (round-3 bug: scalar LDS writes along the channel axis were a 16-way bank
// conflict, 69M conflict cycles). Each thread gathers the 8 channels of its
// fragment directly from global (lane = n/j -> 128/256B coalesced per
// instruction), then stores one b128 per fragment (lanes write consecutive
// 16B chunks = conflict-free).
// fc1 MFMA with W1 as "a" (j via regs) and X as "b" (n via lanes): fc2
// j-reduction = 15 in-register adds + one shfl_xor(32); out col = lane = n.
__global__ __launch_bounds__(256, 3) void head_kernel(
    const ushort* __restrict__ Eh, const ushort* __restrict__ El,
    const ushort* __restrict__ Oh, const ushort* __restrict__ Ol,
    const float* __restrict__ w1, const float* __restrict__ b1,
    const float* __restrict__ w2, const float* __restrict__ b2,
    float* __restrict__ out) {
    __shared__ __align__(16) ushort Xh[4096];  // [kg8][n64][8]  8 KB
    __shared__ __align__(16) ushort Xl[4096];
    __shared__ __align__(16) ushort Wh[8192];  // [kg8][j128][8] 16 KB
    __shared__ __align__(16) ushort Wl[8192];
    __shared__ float part[4][64];
    const int b = blockIdx.y;
    const int n0 = blockIdx.x * 64;
    const int t = threadIdx.x;
    const int lane = t & 63, w = t >> 6;
    const int l32 = lane & 31, lh = lane >> 5;
    const float sg = (n0 < HS) ? 0.5f : -0.5f;  // 0.5 folded into X
    const int nc = n0 & (HS - 1);
    // ---- stage X: wave w gathers channels [w*16, w*16+16) for n = lane.
    // Per-instruction: 64 lanes x 2B consecutive n = 128B coalesced.
    {
        const int n = lane;
        const size_t gx = (size_t)(b * CC + w * 16) * HS + nc + n;
        short8 fh[2], fl[2];
#pragma unroll
        for (int cc = 0; cc < 16; cc++) {
            size_t g = gx + (size_t)cc * HS;
            float e = b2f(Eh[g]) + b2f(El[g]);
            float o = b2f(Oh[g]) + b2f(Ol[g]);
            float x = 0.5f * e + sg * o;
            ushort hh, ll;
            split2(x, hh, ll);
            fh[cc >> 3][cc & 7] = (short)hh;
            fl[cc >> 3][cc & 7] = (short)ll;
        }
        const int kg0 = w * 2;
#pragma unroll
        for (int q = 0; q < 2; q++) {
            *(short8*)&Xh[((kg0 + q) * 64 + n) * 8] = fh[q];
            *(short8*)&Xl[((kg0 + q) * 64 + n) * 8] = fl[q];
        }
    }
    // ---- stage W1: thread handles j = t&127, c in [half*32, half*32+32).
    // Loads lane-consecutive j (256B/instruction); b128 fragment stores.
    {
        const int j = t & 127, half = t >> 7;
#pragma unroll
        for (int q = 0; q < 4; q++) {
            const int kg = half * 4 + q;
            short8 fh, fl;
#pragma unroll
            for (int e = 0; e < 8; e++) {
                int c = kg * 8 + e;
                ushort hh, ll;
                split2(w1[c * 128 + j], hh, ll);
                fh[e] = (short)hh;
                fl[e] = (short)ll;
            }
            *(short8*)&Wh[(kg * 128 + j) * 8] = fh;
            *(short8*)&Wl[(kg * 128 + j) * 8] = fl;
        }
    }
    __syncthreads();
    // ---- fc1 GEMM: wave w owns j-rows [w*32, w*32+32) (via regs), n via lanes
    f32x16 acc[2];
    acc[0] = (f32x16)0.f;
    acc[1] = (f32x16)0.f;
#pragma unroll
    for (int ks = 0; ks < 4; ks++) {
        const int kg = ks * 2 + lh;
        const int offa = (kg * 128 + w * 32 + l32) * 8;
        short8 awh = *(const short8*)&Wh[offa];
        short8 awl = *(const short8*)&Wl[offa];
#pragma unroll
        for (int nt = 0; nt < 2; nt++) {
            const int offb = (kg * 64 + nt * 32 + l32) * 8;
            short8 bxh = *(const short8*)&Xh[offb];
            short8 bxl = *(const short8*)&Xl[offb];
            acc[nt] = __builtin_amdgcn_mfma_f32_32x32x16_bf16(awh, bxh, acc[nt], 0, 0, 0);
            acc[nt] = __builtin_amdgcn_mfma_f32_32x32x16_bf16(awh, bxl, acc[nt], 0, 0, 0);
            acc[nt] = __builtin_amdgcn_mfma_f32_32x32x16_bf16(awl, bxh, acc[nt], 0, 0, 0);
        }
    }
    // ---- fc2 fused: bias + gelu + *w2[j]; reduce over j = regs + lh-swap
#pragma unroll
    for (int nt = 0; nt < 2; nt++) {
        float s = 0.f;
#pragma unroll
        for (int reg = 0; reg < 16; reg++) {
            const int j0 = w * 32 + (reg & 3) + 8 * (reg >> 2) + 4 * lh;
            s += gelu_exact(acc[nt][reg] + b1[j0]) * w2[j0];
        }
        s += __shfl_xor(s, 32);
        part[w][nt * 32 + l32] = s;  // both lh halves write identical value
    }
    __syncthreads();
    if (t < 64)
        out[b * SS + n0 + t] = part[0][t] + part[1][t] + part[2][t] + part[3][t] + b2[0];
}

extern "C" void kernel_launch(void* const* d_in, const int* in_sizes, int n_in,
                              void* d_out, int out_size, void* d_ws, size_t ws_size,
                              hipStream_t stream) {
    (void)in_sizes; (void)n_in; (void)out_size; (void)ws_size;
    const float* u = (const float*)d_in[0];
    const float* fc0_w = (const float*)d_in[1];
    const float* fc0_b = (const float*)d_in[2];
    const float* sw_r = (const float*)d_in[3];
    const float* sw_i = (const float*)d_in[4];
    const float* pw_w = (const float*)d_in[5];
    const float* pw_b = (const float*)d_in[6];
    const float* fc1_w = (const float*)d_in[7];
    const float* fc1_b = (const float*)d_in[8];
    const float* fc2_w = (const float*)d_in[9];
    const float* fc2_b = (const float*)d_in[10];
    float* out = (float*)d_out;

    // workspace layout (total = 167,772,160 B)
    char* ws = (char*)d_ws;
    ushort* Eh = (ushort*)ws;                  // [4096][4096]
    ushort* El = (ushort*)(ws + 33554432);
    ushort* Oh = (ushort*)(ws + 67108864);
    ushort* Ol = (ushort*)(ws + 100663296);
    ushort* t1h = (ushort*)(ws + 134217728);   // [512][4096]
    ushort* t1l = (ushort*)(ws + 138412032);
    ushort* t2h = (ushort*)(ws + 142606336);   // [4096][512]
    ushort* t2l = (ushort*)(ws + 146800640);
    ushort* omh = (ushort*)(ws + 150994944);   // [4096][512]
    ushort* oml = (ushort*)(ws + 155189248);
    float* Xf = (float*)(ws + 159383552);      // [4096][512] fp32

    build_T1p<<<dim3(KK2, HS / 256), 256, 0, stream>>>(t1h, t1l);
    build_T2r<<<dim3(HS, KK2 / 256), 256, 0, stream>>>(t2h, t2l);
    lift_kernel<<<dim3(HS / 256, CC, BB), 256, 0, stream>>>(u, fc0_w, fc0_b, Eh, El,
                                                            Oh, Ol);
    for (int l = 0; l < 4; l++) {
        zero_xf<<<dim3(2048), 256, 0, stream>>>(Xf);
        dft_mfma<<<dim3(1024), 256, 0, stream>>>(Eh, El, Oh, Ol, t1h, t1l, Xf);
        mode_mix<<<dim3(BB / 2, CC / 2), 256, 0, stream>>>(Xf, sw_r, sw_i, omh, oml, l);
        inv_mfma<<<dim3(HS / 64, 32), 256, 0, stream>>>(
            omh, oml, t2h, t2l, pw_w, pw_b, Eh, El, Oh, Ol, l, (l < 3) ? 1 : 0);
    }
    head_kernel<<<dim3(SS / 64, BB), 256, 0, stream>>>(Eh, El, Oh, Ol, fc1_w, fc1_b,
                                                       fc2_w, fc2_b, out);
}

// Round 11
// 1403.797 us; speedup vs baseline: 1.2025x; 1.2025x over previous
//
#include <hip/hip_runtime.h>
#include <hip/hip_bf16.h>
#include <math.h>

#define BB 64      // batch
#define CC 64      // width/channels
#define SS 8192    // sequence
#define HS 4096    // SS/2 (radix-2 half)
#define NMODE 256  // kept rfft modes
#define KK2 512    // 2*NMODE (re/im interleaved, permuted [even-k | odd-k])

typedef __attribute__((ext_vector_type(8))) short short8;
typedef __attribute__((ext_vector_type(16))) float f32x16;

#define VMW12 asm volatile("s_waitcnt vmcnt(12)" ::: "memory")
#define VMW10 asm volatile("s_waitcnt vmcnt(10)" ::: "memory")
#define VMW8 asm volatile("s_waitcnt vmcnt(8)" ::: "memory")
#define VMW4 asm volatile("s_waitcnt vmcnt(4)" ::: "memory")
#define VMW0 asm volatile("s_waitcnt vmcnt(0)" ::: "memory")
#define SBAR asm volatile("s_barrier" ::: "memory")

__device__ __forceinline__ float gelu_exact(float v) {
    return 0.5f * v * (1.0f + erff(v * 0.7071067811865476f));
}
__device__ __forceinline__ float b2f(ushort u) {
    return __uint_as_float(((unsigned int)u) << 16);
}
__device__ __forceinline__ ushort f2b(float v) {
    __hip_bfloat16 h = __float2bfloat16(v);  // RNE
    return *(ushort*)&h;
}
__device__ __forceinline__ void split2(float v, ushort& h, ushort& l) {
    h = f2b(v);
    l = f2b(v - b2f(h));
}
// permuted col -> true frequency k
__device__ __forceinline__ int colk(int c) {
    return (c < 256) ? (c & ~1) : (((c - 256) & ~1) | 1);
}
// async global->LDS DMA, 16B per lane; dest = wave-uniform base + lane*16
__device__ __forceinline__ void dma16(const ushort* g, ushort* l) {
    __builtin_amdgcn_global_load_lds((const __attribute__((address_space(1))) void*)g,
                                     (__attribute__((address_space(3))) void*)l, 16, 0, 0);
}

// ---------------- DFT basis tables (bf16 hi/lo pairs, permuted cols) --------
// T1p[c][n<4096]: forward table (even-k rows pair with E, odd-k with O).
// T2r[n<4096][c]: inverse table. value = ri ? -sin(2πkn/S) : cos(2πkn/S).
__global__ void build_T1p(ushort* __restrict__ h, ushort* __restrict__ l) {
    int c = blockIdx.x;
    int n = blockIdx.y * 256 + threadIdx.x;
    int k = colk(c), ri = c & 1;
    int m = (n * k) & (SS - 1);
    float th = (float)m * (6.283185307179586476925f / (float)SS);
    float s, co;
    sincosf(th, &s, &co);
    float v = ri ? -s : co;
    ushort hh, ll;
    split2(v, hh, ll);
    h[(size_t)c * HS + n] = hh;
    l[(size_t)c * HS + n] = ll;
}

__global__ void build_T2r(ushort* __restrict__ h, ushort* __restrict__ l) {
    int n = blockIdx.x;
    int c = blockIdx.y * 256 + threadIdx.x;
    int k = colk(c), ri = c & 1;
    int m = (n * k) & (SS - 1);
    float th = (float)m * (6.283185307179586476925f / (float)SS);
    float s, co;
    sincosf(th, &s, &co);
    float v = ri ? -s : co;
    ushort hh, ll;
    split2(v, hh, ll);
    h[(size_t)n * KK2 + c] = hh;
    l[(size_t)n * KK2 + c] = ll;
}

__global__ void zero_xf(float* __restrict__ p) {
    size_t i = ((size_t)blockIdx.x * 256 + threadIdx.x) * 4;
    *(float4*)&p[i] = make_float4(0.f, 0.f, 0.f, 0.f);
}

// ---------------- lifting layer (writes split E/O directly) ----------------
__global__ void lift_kernel(const float* __restrict__ u, const float* __restrict__ w0,
                            const float* __restrict__ b0, ushort* __restrict__ Eh,
                            ushort* __restrict__ El, ushort* __restrict__ Oh,
                            ushort* __restrict__ Ol) {
    int n = blockIdx.x * 256 + threadIdx.x;  // 0..4095
    int c = blockIdx.y;
    int b = blockIdx.z;
    float g1 = (float)n * (1.0f / (float)(SS - 1));
    float g2 = (float)(n + HS) * (1.0f / (float)(SS - 1));
    float v1 = u[b * SS + n] * w0[c] + g1 * w0[CC + c] + b0[c];
    float v2 = u[b * SS + n + HS] * w0[c] + g2 * w0[CC + c] + b0[c];
    float E = v1 + v2, O = v1 - v2;
    ushort hh, ll;
    size_t idx = (size_t)(b * CC + c) * HS + n;
    split2(E, hh, ll);
    Eh[idx] = hh;
    El[idx] = ll;
    split2(O, hh, ll);
    Oh[idx] = hh;
    Ol[idx] = ll;
}

// ---------------- forward truncated DFT (radix-2): K=4096 MFMA GEMM --------
// v2 (REVERTED from v3: 8-way k-split doubled atomic RMW traffic, FETCH
// 481MB @ 3TB/s, dur 98->184). DMA+dbuf+counted-vmcnt, 4 k-splits, grid 512
// (2 blk/CU), 2x32KB LDS, vmcnt(8) issue-ahead.
__global__ __launch_bounds__(256, 2) void dft_mfma(
    const ushort* __restrict__ Eh, const ushort* __restrict__ El,
    const ushort* __restrict__ Oh, const ushort* __restrict__ Ol,
    const ushort* __restrict__ t1h, const ushort* __restrict__ t1l,
    float* __restrict__ Xf) {
    __shared__ __align__(16) ushort SM[32768];  // 64 KB: two 32 KB buffers
    const int t = threadIdx.x;
    const int L = blockIdx.x;  // 512 blocks
    const int gq = L >> 5, j = L & 31;
    const int c0 = (j >> 3) * 128;
    const int m0 = ((gq & 3) * 8 + (j & 7)) * 128;
    const int kz = (gq >> 2) * 1024;  // 4 k-splits over K=4096
    const ushort* __restrict__ Ahp = (c0 < 256) ? Eh : Oh;
    const ushort* __restrict__ Alp = (c0 < 256) ? El : Ol;
    const int lane = t & 63, w = t >> 6;
    const int wm = (w >> 1) * 64, wn = (w & 1) * 64;
    const int l32 = lane & 31, lh = lane >> 5;

    f32x16 acc[2][2];
#pragma unroll
    for (int i = 0; i < 2; i++)
#pragma unroll
        for (int jj = 0; jj < 2; jj++) acc[i][jj] = (f32x16)0.f;

    // wave w stages k-slice [kt+8w, kt+8w+8) for rows lane and 64+lane
    // -> LDS [Ah|Al|Bh|Bl][kg=w][row][8]
    const size_t aoff = (size_t)(m0 + lane) * HS + w * 8;
    const size_t boff = (size_t)(c0 + lane) * HS + w * 8;
    const size_t r64 = (size_t)64 * HS;

    auto stage = [&](int kt, int bsel) {
        ushort* base = SM + bsel * 16384;
        ushort* dAh = base + w * 1024;
        ushort* dAl = base + 4096 + w * 1024;
        ushort* dBh = base + 8192 + w * 1024;
        ushort* dBl = base + 12288 + w * 1024;
        dma16(Ahp + aoff + kt, dAh);
        dma16(Ahp + aoff + r64 + kt, dAh + 512);
        dma16(Alp + aoff + kt, dAl);
        dma16(Alp + aoff + r64 + kt, dAl + 512);
        dma16(t1h + boff + kt, dBh);
        dma16(t1h + boff + r64 + kt, dBh + 512);
        dma16(t1l + boff + kt, dBl);
        dma16(t1l + boff + r64 + kt, dBl + 512);
    };
    auto compute = [&](int bsel) {
        const ushort* As_h = SM + bsel * 16384;
        const ushort* As_l = As_h + 4096;
        const ushort* Bs_h = As_h + 8192;
        const ushort* Bs_l = As_h + 12288;
#pragma unroll
        for (int s2 = 0; s2 < 2; s2++) {
            const int kg = s2 * 2 + lh;
            short8 ah[2], al[2], bh2[2], bl2[2];
#pragma unroll
            for (int mt = 0; mt < 2; mt++) {
                int off = (kg * 128 + wm + mt * 32 + l32) * 8;
                ah[mt] = *(const short8*)&As_h[off];
                al[mt] = *(const short8*)&As_l[off];
            }
#pragma unroll
            for (int nt = 0; nt < 2; nt++) {
                int off = (kg * 128 + wn + nt * 32 + l32) * 8;
                bh2[nt] = *(const short8*)&Bs_h[off];
                bl2[nt] = *(const short8*)&Bs_l[off];
            }
#pragma unroll
            for (int nt = 0; nt < 2; nt++)
#pragma unroll
                for (int mt = 0; mt < 2; mt++) {
                    acc[mt][nt] = __builtin_amdgcn_mfma_f32_32x32x16_bf16(ah[mt], bh2[nt], acc[mt][nt], 0, 0, 0);
                    acc[mt][nt] = __builtin_amdgcn_mfma_f32_32x32x16_bf16(ah[mt], bl2[nt], acc[mt][nt], 0, 0, 0);
                    acc[mt][nt] = __builtin_amdgcn_mfma_f32_32x32x16_bf16(al[mt], bh2[nt], acc[mt][nt], 0, 0, 0);
                }
        }
    };

    stage(kz, 0);
#pragma unroll 1
    for (int st = 0; st < 32; st++) {  // 32 K=32 steps over this split's K=1024
        const int buf = st & 1;
        if (st < 31) {
            stage(kz + (st + 1) * 32, buf ^ 1);
            VMW8;  // wait only for step st's 8 DMAs; st+1's stay in flight
        } else {
            VMW0;
        }
        SBAR;
        compute(buf);
        SBAR;
    }
#pragma unroll
    for (int mt = 0; mt < 2; mt++)
#pragma unroll
        for (int nt = 0; nt < 2; nt++) {
            int col = c0 + wn + nt * 32 + l32;
#pragma unroll
            for (int reg = 0; reg < 16; reg++) {
                int row = m0 + wm + mt * 32 + (reg & 3) + 8 * (reg >> 2) + 4 * lh;
                atomicAdd(&Xf[(size_t)row * KK2 + col], acc[mt][nt][reg]);
            }
        }
}

// ---------------- mode mixing (permuted cols) --------------------------------
// GRID SWAPPED (round-11): consecutive blocks now share the same Xf batch-slab
// (blockIdx.x = og-pair, blockIdx.y = bg-pair) -> L2 absorbs the 32x re-read
// (was 268 MB fetch/dispatch with bg-major order).
__global__ __launch_bounds__(256) void mode_mix(const float* __restrict__ Xf,
                                                const float* __restrict__ swr,
                                                const float* __restrict__ swi,
                                                ushort* __restrict__ omh,
                                                ushort* __restrict__ oml, int l) {
    int k = threadIdx.x;
    int og = blockIdx.x * 2;
    int bg = blockIdx.y * 2;
    const int cp = ((k & 1) << 8) | ((k >> 1) << 1);  // permuted re-col
    float ar[2][2] = {}, ai[2][2] = {};
#pragma unroll 2
    for (int i = 0; i < CC; i++) {
        float2 x0 = *(const float2*)&Xf[((size_t)(bg + 0) * CC + i) * KK2 + cp];
        float2 x1 = *(const float2*)&Xf[((size_t)(bg + 1) * CC + i) * KK2 + cp];
        size_t wb = ((size_t)(l * CC + i) * CC + og) * NMODE + k;
        float wr0 = swr[wb], wi0 = swi[wb];
        float wr1 = swr[wb + NMODE], wi1 = swi[wb + NMODE];
        ar[0][0] += x0.x * wr0 - x0.y * wi0;
        ai[0][0] += x0.x * wi0 + x0.y * wr0;
        ar[0][1] += x0.x * wr1 - x0.y * wi1;
        ai[0][1] += x0.x * wi1 + x0.y * wr1;
        ar[1][0] += x1.x * wr0 - x1.y * wi0;
        ai[1][0] += x1.x * wi0 + x1.y * wr0;
        ar[1][1] += x1.x * wr1 - x1.y * wi1;
        ai[1][1] += x1.x * wi1 + x1.y * wr1;
    }
    float ck = (k == 0) ? (1.0f / (float)SS) : (2.0f / (float)SS);
#pragma unroll
    for (int b2 = 0; b2 < 2; b2++)
#pragma unroll
        for (int oo = 0; oo < 2; oo++) {
            float re = ar[b2][oo] * ck;
            float im = ai[b2][oo] * ck;
            ushort hr, lr2, hi2, li2;
            split2(re, hr, lr2);
            split2(im, hi2, li2);
            size_t base = ((size_t)(bg + b2) * CC + og + oo) * KK2 + cp;
            *(ushort2*)&omh[base] = make_ushort2(hr, hi2);
            *(ushort2*)&oml[base] = make_ushort2(lr2, li2);
        }
}

// ---------------- inverse DFT (radix-2) + pointwise + gelu -------------------
// v6: TRIPLE-buffer, depth-2 prefetch. Round-10 post-mortem: v2/v3/v5 all
// ~170us with all pipes <30% -> depth-1 DMA pipeline stalls on L3/HBM latency
// (om/t2 = 16MB > per-XCD L2; step ~300cy < latency ~600-900cy). v5 geometry
// (128 rows x 64 n, wave tile 64x32, 64 acc AGPR), 3 x 24KB slots (72KB,
// 2 blk/CU), issue stage(st+2), steady-state vmcnt(12) = waits only step
// st's 6 DMAs; transition counts: VMW10 @st14 (stage2=4), VMW8 @st15/r0/r1,
// VMW4 @r2, VMW0 @r3. Slot reuse audited: slot(st) last read at st-3's
// compute, barriered before st's issue.
__global__ __launch_bounds__(256, 2) void inv_mfma(
    const ushort* __restrict__ omh, const ushort* __restrict__ oml,
    const ushort* __restrict__ t2h, const ushort* __restrict__ t2l,
    const float* __restrict__ pww, const float* __restrict__ pwb,
    ushort* __restrict__ Eh, ushort* __restrict__ El,
    ushort* __restrict__ Oh, ushort* __restrict__ Ol, int l, int gel) {
    __shared__ __align__(16) ushort SM[36864];  // 72 KB: three 24 KB slots
    const int t = threadIdx.x;
    const int n0 = blockIdx.x * 64;    // n < 4096
    const int row0 = blockIdx.y * 128; // 2 batches x 64 out-ch
    const int lane = t & 63, w = t >> 6;
    const int wm = (w >> 1) * 64, wn = (w & 1) * 32;
    const int l32 = lane & 31, lh = lane >> 5;

    f32x16 aP[2], aQ[2];
    aP[0] = (f32x16)0.f;
    aP[1] = (f32x16)0.f;
    aQ[0] = (f32x16)0.f;
    aQ[1] = (f32x16)0.f;

    // slot layout (ushorts): Ah[kg4][128][8] @0 (4096), Al @4096,
    // Bh[kg4][64][8] @8192 (2048), Bl @10240. Slot stride 12288.
    // staging roles: sel = w>>1 (0=hi, 1=lo arrays), p = w&1 (kg pair)
    const int sel = w >> 1, p = w & 1;
    const ushort* const Asrc = sel ? oml : omh;
    const ushort* const Bsrc = sel ? t2l : t2h;
    const size_t aoff = (size_t)(row0 + lane) * KK2;
    const size_t boff = (size_t)(n0 + lane) * KK2;
    const size_t r64 = (size_t)64 * KK2;

    auto stage1 = [&](int st, int slot) {
        const int kt = st * 32 + 2 * p * 8;
        ushort* dA = SM + slot * 12288 + sel * 4096 + 2 * p * 1024;
        ushort* dB = SM + slot * 12288 + 8192 + sel * 2048 + 2 * p * 512;
        dma16(Asrc + aoff + kt, dA);              // kg=2p,   rows 0..63
        dma16(Asrc + aoff + r64 + kt, dA + 512);  // kg=2p,   rows 64..127
        dma16(Asrc + aoff + kt + 8, dA + 1024);   // kg=2p+1, rows 0..63
        dma16(Asrc + aoff + r64 + kt + 8, dA + 1536);
        dma16(Bsrc + boff + kt, dB);              // kg=2p   (64 n-rows)
        dma16(Bsrc + boff + kt + 8, dB + 512);    // kg=2p+1
    };
    // phase-2: x tile [bs2][ch64][n64] = 16 KB at slot base. Wave w stages
    // bs = w>>1, ch-half = (w&1)*32; chunk q covers 8 ch x 64 n.
    const size_t xsrc = (size_t)(row0 + (w >> 1) * 64 + (w & 1) * 32 + (lane >> 3)) * HS +
                        n0 + (lane & 7) * 8;
    auto stage2 = [&](const ushort* src, int slot) {
        ushort* dX = SM + slot * 12288 + (w >> 1) * 4096 + (w & 1) * 2048;
#pragma unroll
        for (int q = 0; q < 4; q++) dma16(src + xsrc + (size_t)q * 8 * HS, dX + q * 512);
    };
    auto compute1 = [&](f32x16* acc, const int slot) {
        const ushort* base = SM + slot * 12288;
#pragma unroll
        for (int s2 = 0; s2 < 2; s2++) {
            const int kg = s2 * 2 + lh;
            short8 ah[2], al[2];
#pragma unroll
            for (int mt = 0; mt < 2; mt++) {
                int off = (kg * 128 + wm + mt * 32 + l32) * 8;
                ah[mt] = *(const short8*)&base[off];
                al[mt] = *(const short8*)&base[4096 + off];
            }
            const int offb = (kg * 64 + wn + l32) * 8;
            short8 bh = *(const short8*)&base[8192 + offb];
            short8 bl = *(const short8*)&base[10240 + offb];
#pragma unroll
            for (int mt = 0; mt < 2; mt++) {
                acc[mt] = __builtin_amdgcn_mfma_f32_32x32x16_bf16(ah[mt], bh, acc[mt], 0, 0, 0);
                acc[mt] = __builtin_amdgcn_mfma_f32_32x32x16_bf16(ah[mt], bl, acc[mt], 0, 0, 0);
                acc[mt] = __builtin_amdgcn_mfma_f32_32x32x16_bf16(al[mt], bh, acc[mt], 0, 0, 0);
            }
        }
    };

    // ---- phase 1: P (steps 0..7, even-k cols 0..255), Q (steps 8..15) ----
    stage1(0, 0);
    stage1(1, 1);
#pragma unroll 1
    for (int st = 0; st < 8; st++) {
        stage1(st + 2, (st + 2) % 3);
        VMW12;  // drains step st's 6; st+1/st+2 stay in flight
        SBAR;
        compute1(aP, st % 3);
        SBAR;
    }
#pragma unroll 1
    for (int st = 8; st < 14; st++) {
        stage1(st + 2, (st + 2) % 3);
        VMW12;
        SBAR;
        compute1(aQ, st % 3);
        SBAR;
    }
    {  // st = 14: prefetch phase-2 round 0 (Eh) into slot (16)%3 = 1
        stage2(Eh, 1);
        VMW10;  // outstanding = st14(6)+st15(6)+r0(4); drain st14's 6
        SBAR;
        compute1(aQ, 2);  // slot(14) = 2
        SBAR;
    }
    {  // st = 15: prefetch round 1 (El) into slot (17)%3 = 2
        stage2(El, 2);
        VMW8;  // outstanding = st15(6)+r0(4)+r1(4); drain st15's 6
        SBAR;
        compute1(aQ, 0);  // slot(15) = 0
        SBAR;
    }
    // butterfly (register-local): aP := u = P+Q (y[n]), aQ := v = P-Q
#pragma unroll
    for (int mt = 0; mt < 2; mt++) {
        f32x16 pp2 = aP[mt];
        aP[mt] = pp2 + aQ[mt];
        aQ[mt] = pp2 - aQ[mt];
    }
    // hoisted pw fragments (pw/2, bf16 hi/lo); channel index = mt*32 + l32
    short8 pah[4][2], pal[4][2];
#pragma unroll
    for (int ks = 0; ks < 4; ks++)
#pragma unroll
        for (int mt = 0; mt < 2; mt++) {
            const float* pp = &pww[(size_t)(l * CC + mt * 32 + l32) * CC + ks * 16 + lh * 8];
            float4 pa = *(const float4*)pp;
            float4 pb = *(const float4*)(pp + 4);
            float pv[8] = {pa.x, pa.y, pa.z, pa.w, pb.x, pb.y, pb.z, pb.w};
#pragma unroll
            for (int e = 0; e < 8; e++) {
                ushort h2, l2;
                split2(0.5f * pv[e], h2, l2);
                pah[ks][mt][e] = (short)h2;
                pal[ks][mt][e] = (short)l2;
            }
        }
    // ---- phase 2: 4 rounds (Eh, El, Oh, Ol), slots (16+r)%3 = 1,2,0,1 ----
    const int bsw = w >> 1;
#pragma unroll 1
    for (int r = 0; r < 4; r++) {
        const int slot = (16 + r) % 3;
        const bool isO = (r >= 2), isHi = !(r & 1);
        if (r == 0) {
            stage2(Oh, 0);  // slot (18)%3 = 0, last read at st15 (barriered)
            VMW8;           // drain r0's 4 (pw loads already drained by compiler wait)
        } else if (r == 1) {
            stage2(Ol, 1);  // slot (19)%3 = 1, last read at r0 (barriered)
            VMW8;           // outstanding = r1(4)+r2(4)+r3(4); drain r1
        } else if (r == 2) {
            VMW4;           // outstanding = r2(4)+r3(4); drain r2
        } else {
            VMW0;
        }
        SBAR;
        const ushort* base = SM + slot * 12288;
#pragma unroll
        for (int ks = 0; ks < 4; ks++) {
            short8 bf, nbf;
            const int rb = (bsw * 64 + ks * 16 + lh * 8) * 64 + wn + l32;
#pragma unroll
            for (int jj = 0; jj < 8; jj++) bf[jj] = (short)base[rb + jj * 64];
            if (isO) {
#pragma unroll
                for (int jj = 0; jj < 8; jj++) nbf[jj] = (short)(bf[jj] ^ (short)0x8000);
            }
#pragma unroll
            for (int mt = 0; mt < 2; mt++) {
                aP[mt] = __builtin_amdgcn_mfma_f32_32x32x16_bf16(pah[ks][mt], bf, aP[mt], 0, 0, 0);
                aQ[mt] = __builtin_amdgcn_mfma_f32_32x32x16_bf16(pah[ks][mt], isO ? nbf : bf, aQ[mt], 0, 0, 0);
                if (isHi) {
                    aP[mt] = __builtin_amdgcn_mfma_f32_32x32x16_bf16(pal[ks][mt], bf, aP[mt], 0, 0, 0);
                    aQ[mt] = __builtin_amdgcn_mfma_f32_32x32x16_bf16(pal[ks][mt], isO ? nbf : bf, aQ[mt], 0, 0, 0);
                }
            }
        }
        if (r < 3) SBAR;  // readers done before a later round's DMA reuses slot
    }
    // epilogue: bias + gelu on both halves, butterfly to E/O, split-store
#pragma unroll
    for (int mt = 0; mt < 2; mt++)
#pragma unroll
        for (int reg = 0; reg < 16; reg++) {
            int roffs = (reg & 3) + 8 * (reg >> 2) + 4 * lh;
            float bias = pwb[l * CC + mt * 32 + roffs];
            float uu = aP[mt][reg] + bias;
            float vv = aQ[mt][reg] + bias;
            if (gel) {
                uu = gelu_exact(uu);
                vv = gelu_exact(vv);
            }
            float EE = uu + vv, OO = uu - vv;
            ushort h2, l2;
            size_t gg = (size_t)(row0 + wm + mt * 32 + roffs) * HS + n0 + wn + l32;
            split2(EE, h2, l2);
            Eh[gg] = h2;
            El[gg] = l2;
            split2(OO, h2, l2);
            Oh[gg] = h2;
            Ol[gg] = l2;
        }
}

// ---------------- projection head (MFMA, register-transpose staging) --------
// Block: one (b, 64-position) tile. Fragment assembly happens in REGISTERS
// (round-3 bug: scalar LDS writes along the channel axis were a 16-way bank
// conflict, 69M conflict cycles). Each thread gathers the 8 channels of its
// fragment directly from global (lane = n/j -> 128/256B coalesced per
// instruction), then stores one b128 per fragment (lanes write consecutive
// 16B chunks = conflict-free).
// fc1 MFMA with W1 as "a" (j via regs) and X as "b" (n via lanes): fc2
// j-reduction = 15 in-register adds + one shfl_xor(32); out col = lane = n.
__global__ __launch_bounds__(256, 3) void head_kernel(
    const ushort* __restrict__ Eh, const ushort* __restrict__ El,
    const ushort* __restrict__ Oh, const ushort* __restrict__ Ol,
    const float* __restrict__ w1, const float* __restrict__ b1,
    const float* __restrict__ w2, const float* __restrict__ b2,
    float* __restrict__ out) {
    __shared__ __align__(16) ushort Xh[4096];  // [kg8][n64][8]  8 KB
    __shared__ __align__(16) ushort Xl[4096];
    __shared__ __align__(16) ushort Wh[8192];  // [kg8][j128][8] 16 KB
    __shared__ __align__(16) ushort Wl[8192];
    __shared__ float part[4][64];
    const int b = blockIdx.y;
    const int n0 = blockIdx.x * 64;
    const int t = threadIdx.x;
    const int lane = t & 63, w = t >> 6;
    const int l32 = lane & 31, lh = lane >> 5;
    const float sg = (n0 < HS) ? 0.5f : -0.5f;  // 0.5 folded into X
    const int nc = n0 & (HS - 1);
    // ---- stage X: wave w gathers channels [w*16, w*16+16) for n = lane.
    // Per-instruction: 64 lanes x 2B consecutive n = 128B coalesced.
    {
        const int n = lane;
        const size_t gx = (size_t)(b * CC + w * 16) * HS + nc + n;
        short8 fh[2], fl[2];
#pragma unroll
        for (int cc = 0; cc < 16; cc++) {
            size_t g = gx + (size_t)cc * HS;
            float e = b2f(Eh[g]) + b2f(El[g]);
            float o = b2f(Oh[g]) + b2f(Ol[g]);
            float x = 0.5f * e + sg * o;
            ushort hh, ll;
            split2(x, hh, ll);
            fh[cc >> 3][cc & 7] = (short)hh;
            fl[cc >> 3][cc & 7] = (short)ll;
        }
        const int kg0 = w * 2;
#pragma unroll
        for (int q = 0; q < 2; q++) {
            *(short8*)&Xh[((kg0 + q) * 64 + n) * 8] = fh[q];
            *(short8*)&Xl[((kg0 + q) * 64 + n) * 8] = fl[q];
        }
    }
    // ---- stage W1: thread handles j = t&127, c in [half*32, half*32+32).
    // Loads lane-consecutive j (256B/instruction); b128 fragment stores.
    {
        const int j = t & 127, half = t >> 7;
#pragma unroll
        for (int q = 0; q < 4; q++) {
            const int kg = half * 4 + q;
            short8 fh, fl;
#pragma unroll
            for (int e = 0; e < 8; e++) {
                int c = kg * 8 + e;
                ushort hh, ll;
                split2(w1[c * 128 + j], hh, ll);
                fh[e] = (short)hh;
                fl[e] = (short)ll;
            }
            *(short8*)&Wh[(kg * 128 + j) * 8] = fh;
            *(short8*)&Wl[(kg * 128 + j) * 8] = fl;
        }
    }
    __syncthreads();
    // ---- fc1 GEMM: wave w owns j-rows [w*32, w*32+32) (via regs), n via lanes
    f32x16 acc[2];
    acc[0] = (f32x16)0.f;
    acc[1] = (f32x16)0.f;
#pragma unroll
    for (int ks = 0; ks < 4; ks++) {
        const int kg = ks * 2 + lh;
        const int offa = (kg * 128 + w * 32 + l32) * 8;
        short8 awh = *(const short8*)&Wh[offa];
        short8 awl = *(const short8*)&Wl[offa];
#pragma unroll
        for (int nt = 0; nt < 2; nt++) {
            const int offb = (kg * 64 + nt * 32 + l32) * 8;
            short8 bxh = *(const short8*)&Xh[offb];
            short8 bxl = *(const short8*)&Xl[offb];
            acc[nt] = __builtin_amdgcn_mfma_f32_32x32x16_bf16(awh, bxh, acc[nt], 0, 0, 0);
            acc[nt] = __builtin_amdgcn_mfma_f32_32x32x16_bf16(awh, bxl, acc[nt], 0, 0, 0);
            acc[nt] = __builtin_amdgcn_mfma_f32_32x32x16_bf16(awl, bxh, acc[nt], 0, 0, 0);
        }
    }
    // ---- fc2 fused: bias + gelu + *w2[j]; reduce over j = regs + lh-swap
#pragma unroll
    for (int nt = 0; nt < 2; nt++) {
        float s = 0.f;
#pragma unroll
        for (int reg = 0; reg < 16; reg++) {
            const int j0 = w * 32 + (reg & 3) + 8 * (reg >> 2) + 4 * lh;
            s += gelu_exact(acc[nt][reg] + b1[j0]) * w2[j0];
        }
        s += __shfl_xor(s, 32);
        part[w][nt * 32 + l32] = s;  // both lh halves write identical value
    }
    __syncthreads();
    if (t < 64)
        out[b * SS + n0 + t] = part[0][t] + part[1][t] + part[2][t] + part[3][t] + b2[0];
}

extern "C" void kernel_launch(void* const* d_in, const int* in_sizes, int n_in,
                              void* d_out, int out_size, void* d_ws, size_t ws_size,
                              hipStream_t stream) {
    (void)in_sizes; (void)n_in; (void)out_size; (void)ws_size;
    const float* u = (const float*)d_in[0];
    const float* fc0_w = (const float*)d_in[1];
    const float* fc0_b = (const float*)d_in[2];
    const float* sw_r = (const float*)d_in[3];
    const float* sw_i = (const float*)d_in[4];
    const float* pw_w = (const float*)d_in[5];
    const float* pw_b = (const float*)d_in[6];
    const float* fc1_w = (const float*)d_in[7];
    const float* fc1_b = (const float*)d_in[8];
    const float* fc2_w = (const float*)d_in[9];
    const float* fc2_b = (const float*)d_in[10];
    float* out = (float*)d_out;

    // workspace layout (total = 167,772,160 B)
    char* ws = (char*)d_ws;
    ushort* Eh = (ushort*)ws;                  // [4096][4096]
    ushort* El = (ushort*)(ws + 33554432);
    ushort* Oh = (ushort*)(ws + 67108864);
    ushort* Ol = (ushort*)(ws + 100663296);
    ushort* t1h = (ushort*)(ws + 134217728);   // [512][4096]
    ushort* t1l = (ushort*)(ws + 138412032);
    ushort* t2h = (ushort*)(ws + 142606336);   // [4096][512]
    ushort* t2l = (ushort*)(ws + 146800640);
    ushort* omh = (ushort*)(ws + 150994944);   // [4096][512]
    ushort* oml = (ushort*)(ws + 155189248);
    float* Xf = (float*)(ws + 159383552);      // [4096][512] fp32

    build_T1p<<<dim3(KK2, HS / 256), 256, 0, stream>>>(t1h, t1l);
    build_T2r<<<dim3(HS, KK2 / 256), 256, 0, stream>>>(t2h, t2l);
    lift_kernel<<<dim3(HS / 256, CC, BB), 256, 0, stream>>>(u, fc0_w, fc0_b, Eh, El,
                                                            Oh, Ol);
    for (int l = 0; l < 4; l++) {
        zero_xf<<<dim3(2048), 256, 0, stream>>>(Xf);
        dft_mfma<<<dim3(512), 256, 0, stream>>>(Eh, El, Oh, Ol, t1h, t1l, Xf);
        mode_mix<<<dim3(CC / 2, BB / 2), 256, 0, stream>>>(Xf, sw_r, sw_i, omh, oml, l);
        inv_mfma<<<dim3(HS / 64, 32), 256, 0, stream>>>(
            omh, oml, t2h, t2l, pw_w, pw_b, Eh, El, Oh, Ol, l, (l < 3) ? 1 : 0);
    }
    head_kernel<<<dim3(SS / 64, BB), 256, 0, stream>>>(Eh, El, Oh, Ol, fc1_w, fc1_b,
                                                       fc2_w, fc2_b, out);
}

// Round 12
// 1263.911 us; speedup vs baseline: 1.3356x; 1.1107x over previous
//
#include <hip/hip_runtime.h>
#include <hip/hip_bf16.h>
#include <math.h>

#define BB 64      // batch
#define CC 64      // width/channels
#define SS 8192    // sequence
#define HS 4096    // SS/2 (radix-2 half)
#define NMODE 256  // kept rfft modes
#define KK2 512    // 2*NMODE (re/im interleaved, permuted [even-k | odd-k])

typedef __attribute__((ext_vector_type(8))) short short8;
typedef __attribute__((ext_vector_type(16))) float f32x16;

#define VMW8 asm volatile("s_waitcnt vmcnt(8)" ::: "memory")
#define VMW0 asm volatile("s_waitcnt vmcnt(0)" ::: "memory")
#define SBAR asm volatile("s_barrier" ::: "memory")

__device__ __forceinline__ float gelu_exact(float v) {
    return 0.5f * v * (1.0f + erff(v * 0.7071067811865476f));
}
__device__ __forceinline__ float b2f(ushort u) {
    return __uint_as_float(((unsigned int)u) << 16);
}
__device__ __forceinline__ ushort f2b(float v) {
    __hip_bfloat16 h = __float2bfloat16(v);  // RNE
    return *(ushort*)&h;
}
__device__ __forceinline__ void split2(float v, ushort& h, ushort& l) {
    h = f2b(v);
    l = f2b(v - b2f(h));
}
// permuted col -> true frequency k
__device__ __forceinline__ int colk(int c) {
    return (c < 256) ? (c & ~1) : (((c - 256) & ~1) | 1);
}
// async global->LDS DMA, 16B per lane; dest = wave-uniform base + lane*16
__device__ __forceinline__ void dma16(const ushort* g, ushort* l) {
    __builtin_amdgcn_global_load_lds((const __attribute__((address_space(1))) void*)g,
                                     (__attribute__((address_space(3))) void*)l, 16, 0, 0);
}

// ---------------- DFT basis tables (bf16 hi/lo pairs, permuted cols) --------
// T1p[c][n<4096]: forward table (even-k rows pair with E, odd-k with O).
// T2r[n<4096][c]: inverse table. value = ri ? -sin(2πkn/S) : cos(2πkn/S).
__global__ void build_T1p(ushort* __restrict__ h, ushort* __restrict__ l) {
    int c = blockIdx.x;
    int n = blockIdx.y * 256 + threadIdx.x;
    int k = colk(c), ri = c & 1;
    int m = (n * k) & (SS - 1);
    float th = (float)m * (6.283185307179586476925f / (float)SS);
    float s, co;
    sincosf(th, &s, &co);
    float v = ri ? -s : co;
    ushort hh, ll;
    split2(v, hh, ll);
    h[(size_t)c * HS + n] = hh;
    l[(size_t)c * HS + n] = ll;
}

__global__ void build_T2r(ushort* __restrict__ h, ushort* __restrict__ l) {
    int n = blockIdx.x;
    int c = blockIdx.y * 256 + threadIdx.x;
    int k = colk(c), ri = c & 1;
    int m = (n * k) & (SS - 1);
    float th = (float)m * (6.283185307179586476925f / (float)SS);
    float s, co;
    sincosf(th, &s, &co);
    float v = ri ? -s : co;
    ushort hh, ll;
    split2(v, hh, ll);
    h[(size_t)n * KK2 + c] = hh;
    l[(size_t)n * KK2 + c] = ll;
}

// ---------------- lifting layer (writes split E/O directly) ----------------
__global__ void lift_kernel(const float* __restrict__ u, const float* __restrict__ w0,
                            const float* __restrict__ b0, ushort* __restrict__ Eh,
                            ushort* __restrict__ El, ushort* __restrict__ Oh,
                            ushort* __restrict__ Ol) {
    int n = blockIdx.x * 256 + threadIdx.x;  // 0..4095
    int c = blockIdx.y;
    int b = blockIdx.z;
    float g1 = (float)n * (1.0f / (float)(SS - 1));
    float g2 = (float)(n + HS) * (1.0f / (float)(SS - 1));
    float v1 = u[b * SS + n] * w0[c] + g1 * w0[CC + c] + b0[c];
    float v2 = u[b * SS + n + HS] * w0[c] + g2 * w0[CC + c] + b0[c];
    float E = v1 + v2, O = v1 - v2;
    ushort hh, ll;
    size_t idx = (size_t)(b * CC + c) * HS + n;
    split2(E, hh, ll);
    Eh[idx] = hh;
    El[idx] = ll;
    split2(O, hh, ll);
    Oh[idx] = hh;
    Ol[idx] = ll;
}

// ---------------- forward truncated DFT (radix-2): K=4096 MFMA GEMM --------
// ORIGINAL version (reg-roundtrip staging, lb(256,3), 32KB LDS) -- RESTORED:
// cross-round accounting showed the DMA port (R9) was ~27us/dispatch SLOWER
// for this kernel (R5 remainder 531 vs R9 remainder 639). Xf[4096][512p] +=
// A[m][n<4096] * T1p[c][n]; A = E for c<256 (even k), O otherwise. K split
// 4 ways, atomic accumulate; 2-barrier K=32 steps with register prefetch.
__global__ __launch_bounds__(256, 3) void dft_mfma(
    const ushort* __restrict__ Eh, const ushort* __restrict__ El,
    const ushort* __restrict__ Oh, const ushort* __restrict__ Ol,
    const ushort* __restrict__ t1h, const ushort* __restrict__ t1l,
    float* __restrict__ Xf) {
    __shared__ __align__(16) ushort SM[16384];  // 32 KB
    ushort* As_h = SM;
    ushort* As_l = SM + 4096;
    ushort* Bs_h = SM + 8192;
    ushort* Bs_l = SM + 12288;
    const int t = threadIdx.x;
    const int L = blockIdx.x;  // 512 blocks
    const int gq = L >> 5, j = L & 31;
    const int c0 = (j >> 3) * 128;
    const int m0 = ((gq & 3) * 8 + (j & 7)) * 128;
    const int kz = (gq >> 2) * 1024;  // 4 k-splits over K=4096
    const ushort* __restrict__ Ahp = (c0 < 256) ? Eh : Oh;
    const ushort* __restrict__ Alp = (c0 < 256) ? El : Ol;
    const int lane = t & 63, w = t >> 6;
    const int wm = (w >> 1) * 64, wn = (w & 1) * 64;
    const int l32 = lane & 31, lh = lane >> 5;
    const int sr = t >> 1, sh = (t & 1) * 16;
    const int g0 = (t & 1) * 2;
    const int d0 = ((g0 + 0) * 128 + sr) * 8;
    const int d1 = ((g0 + 1) * 128 + sr) * 8;

    f32x16 acc[2][2];
#pragma unroll
    for (int i = 0; i < 2; i++)
#pragma unroll
        for (int jj = 0; jj < 2; jj++) acc[i][jj] = (f32x16)0.f;

    const size_t arow = (size_t)(m0 + sr) * HS;
    const size_t brow = (size_t)(c0 + sr) * HS;
    const int kend = kz + 1024;

    short8 a0h, a1h, a0l, a1l, b0h, b1h, b0l, b1l;
    {
        const size_t ga = arow + kz + sh;
        const size_t gb = brow + kz + sh;
        a0h = *(const short8*)&Ahp[ga];
        a1h = *(const short8*)&Ahp[ga + 8];
        a0l = *(const short8*)&Alp[ga];
        a1l = *(const short8*)&Alp[ga + 8];
        b0h = *(const short8*)&t1h[gb];
        b1h = *(const short8*)&t1h[gb + 8];
        b0l = *(const short8*)&t1l[gb];
        b1l = *(const short8*)&t1l[gb + 8];
    }
    for (int kt = kz; kt < kend; kt += 32) {
        __syncthreads();
        *(short8*)&As_h[d0] = a0h;
        *(short8*)&As_h[d1] = a1h;
        *(short8*)&As_l[d0] = a0l;
        *(short8*)&As_l[d1] = a1l;
        *(short8*)&Bs_h[d0] = b0h;
        *(short8*)&Bs_h[d1] = b1h;
        *(short8*)&Bs_l[d0] = b0l;
        *(short8*)&Bs_l[d1] = b1l;
        __syncthreads();
        const int ktn = (kt + 32 < kend) ? kt + 32 : kz;
        const size_t ga = arow + ktn + sh;
        const size_t gb = brow + ktn + sh;
        a0h = *(const short8*)&Ahp[ga];
        a1h = *(const short8*)&Ahp[ga + 8];
        a0l = *(const short8*)&Alp[ga];
        a1l = *(const short8*)&Alp[ga + 8];
        b0h = *(const short8*)&t1h[gb];
        b1h = *(const short8*)&t1h[gb + 8];
        b0l = *(const short8*)&t1l[gb];
        b1l = *(const short8*)&t1l[gb + 8];
#pragma unroll
        for (int s2 = 0; s2 < 2; s2++) {
            const int kg = s2 * 2 + lh;
            short8 ah[2], al[2], bh2[2], bl2[2];
#pragma unroll
            for (int mt = 0; mt < 2; mt++) {
                int off = (kg * 128 + wm + mt * 32 + l32) * 8;
                ah[mt] = *(const short8*)&As_h[off];
                al[mt] = *(const short8*)&As_l[off];
            }
#pragma unroll
            for (int nt = 0; nt < 2; nt++) {
                int off = (kg * 128 + wn + nt * 32 + l32) * 8;
                bh2[nt] = *(const short8*)&Bs_h[off];
                bl2[nt] = *(const short8*)&Bs_l[off];
            }
#pragma unroll
            for (int nt = 0; nt < 2; nt++)
#pragma unroll
                for (int mt = 0; mt < 2; mt++) {
                    acc[mt][nt] = __builtin_amdgcn_mfma_f32_32x32x16_bf16(ah[mt], bh2[nt], acc[mt][nt], 0, 0, 0);
                    acc[mt][nt] = __builtin_amdgcn_mfma_f32_32x32x16_bf16(ah[mt], bl2[nt], acc[mt][nt], 0, 0, 0);
                    acc[mt][nt] = __builtin_amdgcn_mfma_f32_32x32x16_bf16(al[mt], bh2[nt], acc[mt][nt], 0, 0, 0);
                }
        }
    }
#pragma unroll
    for (int mt = 0; mt < 2; mt++)
#pragma unroll
        for (int nt = 0; nt < 2; nt++) {
            int col = c0 + wn + nt * 32 + l32;
#pragma unroll
            for (int reg = 0; reg < 16; reg++) {
                int row = m0 + wm + mt * 32 + (reg & 3) + 8 * (reg >> 2) + 4 * lh;
                atomicAdd(&Xf[(size_t)row * KK2 + col], acc[mt][nt][reg]);
            }
        }
}

// ---------------- mode mixing (permuted cols, original grid) -----------------
__global__ __launch_bounds__(256) void mode_mix(const float* __restrict__ Xf,
                                                const float* __restrict__ swr,
                                                const float* __restrict__ swi,
                                                ushort* __restrict__ omh,
                                                ushort* __restrict__ oml, int l) {
    int k = threadIdx.x;
    int bg = blockIdx.x * 2;
    int og = blockIdx.y * 2;
    const int cp = ((k & 1) << 8) | ((k >> 1) << 1);  // permuted re-col
    float ar[2][2] = {}, ai[2][2] = {};
#pragma unroll 2
    for (int i = 0; i < CC; i++) {
        float2 x0 = *(const float2*)&Xf[((size_t)(bg + 0) * CC + i) * KK2 + cp];
        float2 x1 = *(const float2*)&Xf[((size_t)(bg + 1) * CC + i) * KK2 + cp];
        size_t wb = ((size_t)(l * CC + i) * CC + og) * NMODE + k;
        float wr0 = swr[wb], wi0 = swi[wb];
        float wr1 = swr[wb + NMODE], wi1 = swi[wb + NMODE];
        ar[0][0] += x0.x * wr0 - x0.y * wi0;
        ai[0][0] += x0.x * wi0 + x0.y * wr0;
        ar[0][1] += x0.x * wr1 - x0.y * wi1;
        ai[0][1] += x0.x * wi1 + x0.y * wr1;
        ar[1][0] += x1.x * wr0 - x1.y * wi0;
        ai[1][0] += x1.x * wi0 + x1.y * wr0;
        ar[1][1] += x1.x * wr1 - x1.y * wi1;
        ai[1][1] += x1.x * wi1 + x1.y * wr1;
    }
    float ck = (k == 0) ? (1.0f / (float)SS) : (2.0f / (float)SS);
#pragma unroll
    for (int b2 = 0; b2 < 2; b2++)
#pragma unroll
        for (int oo = 0; oo < 2; oo++) {
            float re = ar[b2][oo] * ck;
            float im = ai[b2][oo] * ck;
            ushort hr, lr2, hi2, li2;
            split2(re, hr, lr2);
            split2(im, hi2, li2);
            size_t base = ((size_t)(bg + b2) * CC + og + oo) * KK2 + cp;
            *(ushort2*)&omh[base] = make_ushort2(hr, hi2);
            *(ushort2*)&oml[base] = make_ushort2(lr2, li2);
        }
}

// ---------------- inverse DFT (radix-2) + pointwise + gelu -------------------
// v3 (BEST MEASURED: 169-170us warm). 4-wave 128x128 tile, double-buffered
// LDS, counted vmcnt(8) + raw s_barrier issue-ahead staging; phase-2 round 0
// prefetched during phase-1 step 15; rounds chain. Failed alternatives:
// v4 wave-split (spilled, 320), v5 small-tile 3-wave (~170, flat), v6
// depth-2 triple-buffer (188, slower).
__global__ __launch_bounds__(256, 2) void inv_mfma(
    const ushort* __restrict__ omh, const ushort* __restrict__ oml,
    const ushort* __restrict__ t2h, const ushort* __restrict__ t2l,
    const float* __restrict__ pww, const float* __restrict__ pwb,
    ushort* __restrict__ Eh, ushort* __restrict__ El,
    ushort* __restrict__ Oh, ushort* __restrict__ Ol, int l, int gel) {
    __shared__ __align__(16) ushort SM[32768];  // 64 KB: two 32 KB buffers
    const int t = threadIdx.x;
    const int n0 = blockIdx.x * 128;   // n < 4096
    const int row0 = blockIdx.y * 128; // 2 batches x 64 out-ch
    const int lane = t & 63, w = t >> 6;
    const int wm = (w >> 1) * 64, wn = (w & 1) * 64;
    const int l32 = lane & 31, lh = lane >> 5;

    f32x16 aP[2][2], aQ[2][2];
#pragma unroll
    for (int i = 0; i < 2; i++)
#pragma unroll
        for (int jj = 0; jj < 2; jj++) {
            aP[i][jj] = (f32x16)0.f;
            aQ[i][jj] = (f32x16)0.f;
        }

    // phase-1 DMA source bases: wave w stages k-slice [kt+8w, kt+8w+8) for
    // rows lane and 64+lane -> LDS buf: [Ah|Al|Bh|Bl][kg=w][row][8]
    const size_t aoff = (size_t)(row0 + lane) * KK2 + w * 8;
    const size_t boff = (size_t)(n0 + lane) * KK2 + w * 8;
    const size_t rstep = (size_t)64 * KK2;

    auto stage1 = [&](int st, int bsel) {
        const int kt = st * 32;
        ushort* base = SM + bsel * 16384;
        ushort* dAh = base + w * 1024;
        ushort* dAl = base + 4096 + w * 1024;
        ushort* dBh = base + 8192 + w * 1024;
        ushort* dBl = base + 12288 + w * 1024;
        dma16(omh + aoff + kt, dAh);
        dma16(omh + aoff + rstep + kt, dAh + 512);
        dma16(oml + aoff + kt, dAl);
        dma16(oml + aoff + rstep + kt, dAl + 512);
        dma16(t2h + boff + kt, dBh);
        dma16(t2h + boff + rstep + kt, dBh + 512);
        dma16(t2l + boff + kt, dBl);
        dma16(t2l + boff + rstep + kt, dBl + 512);
    };
    // phase-2 DMA: chunk = w*512 + q*64 + lane (16B units) ->
    //   bs = w>>1, i = (w&1)*32 + q*4 + (lane>>4), nc = lane&15
    const size_t xsrc = (size_t)(row0 + (w >> 1) * 64 + (w & 1) * 32 + (lane >> 4)) * HS +
                        n0 + (lane & 15) * 8;
    auto stage2 = [&](const ushort* src, int bsel) {
        ushort* dX = SM + bsel * 16384 + w * 4096;
#pragma unroll
        for (int q = 0; q < 8; q++) dma16(src + xsrc + (size_t)q * 4 * HS, dX + q * 512);
    };
    auto compute1 = [&](f32x16 (&acc)[2][2], const int bsel) {
        const ushort* base = SM + bsel * 16384;
#pragma unroll
        for (int s2 = 0; s2 < 2; s2++) {
            const int kg = s2 * 2 + lh;
            short8 ah[2], al[2], bh2[2], bl2[2];
#pragma unroll
            for (int mt = 0; mt < 2; mt++) {
                int off = (kg * 128 + wm + mt * 32 + l32) * 8;
                ah[mt] = *(const short8*)&base[off];
                al[mt] = *(const short8*)&base[4096 + off];
            }
#pragma unroll
            for (int nt = 0; nt < 2; nt++) {
                int off = (kg * 128 + wn + nt * 32 + l32) * 8;
                bh2[nt] = *(const short8*)&base[8192 + off];
                bl2[nt] = *(const short8*)&base[12288 + off];
            }
#pragma unroll
            for (int nt = 0; nt < 2; nt++)
#pragma unroll
                for (int mt = 0; mt < 2; mt++) {
                    acc[mt][nt] = __builtin_amdgcn_mfma_f32_32x32x16_bf16(ah[mt], bh2[nt], acc[mt][nt], 0, 0, 0);
                    acc[mt][nt] = __builtin_amdgcn_mfma_f32_32x32x16_bf16(ah[mt], bl2[nt], acc[mt][nt], 0, 0, 0);
                    acc[mt][nt] = __builtin_amdgcn_mfma_f32_32x32x16_bf16(al[mt], bh2[nt], acc[mt][nt], 0, 0, 0);
                }
        }
    };

    // ---- phase 1: P (steps 0..7, even-k cols 0..255), Q (steps 8..15) ----
    stage1(0, 0);
#pragma unroll 1
    for (int st = 0; st < 8; st++) {
        const int buf = st & 1;
        stage1(st + 1, buf ^ 1);
        VMW8;
        SBAR;
        compute1(aP, buf);
        SBAR;
    }
#pragma unroll 1
    for (int st = 8; st < 15; st++) {
        const int buf = st & 1;
        stage1(st + 1, buf ^ 1);
        VMW8;
        SBAR;
        compute1(aQ, buf);
        SBAR;
    }
    {  // st = 15 (buf 1): prefetch phase-2 round 0 (Eh tile) into buf 0
        stage2(Eh, 0);
        VMW8;
        SBAR;
        compute1(aQ, 1);
        SBAR;
    }
    // butterfly: aP := u = P+Q (y[n]), aQ := v = P-Q (y[n+HS])
#pragma unroll
    for (int mt = 0; mt < 2; mt++)
#pragma unroll
        for (int nt = 0; nt < 2; nt++) {
            f32x16 p = aP[mt][nt];
            aP[mt][nt] = p + aQ[mt][nt];
            aQ[mt][nt] = p - aQ[mt][nt];
        }
    // hoisted pw fragments (pw/2, bf16 hi/lo) for all (ks, mt).
    // output-channel index = mt*32 + l32 (wm is the batch half, NOT a channel)
    short8 pah[4][2], pal[4][2];
#pragma unroll
    for (int ks = 0; ks < 4; ks++)
#pragma unroll
        for (int mt = 0; mt < 2; mt++) {
            const float* pp = &pww[(size_t)(l * CC + mt * 32 + l32) * CC + ks * 16 + lh * 8];
            float4 pa = *(const float4*)pp;
            float4 pb = *(const float4*)(pp + 4);
            float pv[8] = {pa.x, pa.y, pa.z, pa.w, pb.x, pb.y, pb.z, pb.w};
#pragma unroll
            for (int e = 0; e < 8; e++) {
                ushort h2, l2;
                split2(0.5f * pv[e], h2, l2);
                pah[ks][mt][e] = (short)h2;
                pal[ks][mt][e] = (short)l2;
            }
        }
    // ---- phase 2: pointwise, 4 chained rounds: Eh, El, Oh, Ol tiles
    // (2 bs x 64 ch x 128 n, unpadded [bs][i][128] per 32KB buffer)
    const int bsw = w >> 1;
    const ushort* const srcs[4] = {Eh, El, Oh, Ol};
#pragma unroll
    for (int r = 0; r < 4; r++) {
        const int buf = r & 1;
        const bool isO = (r >= 2), isHi = !(r & 1);
        if (r < 3) {
            stage2(srcs[r + 1], buf ^ 1);
            VMW8;
        } else {
            VMW0;
        }
        SBAR;
        const ushort* base = SM + buf * 16384;
#pragma unroll
        for (int ks = 0; ks < 4; ks++) {
            short8 bf[2], nbf[2];
#pragma unroll
            for (int nt = 0; nt < 2; nt++) {
                const int rb = (bsw * 64 + ks * 16 + lh * 8) * 128 + wn + nt * 32 + l32;
#pragma unroll
                for (int jj = 0; jj < 8; jj++) bf[nt][jj] = (short)base[rb + jj * 128];
                if (isO) {
#pragma unroll
                    for (int jj = 0; jj < 8; jj++)
                        nbf[nt][jj] = (short)(bf[nt][jj] ^ (short)0x8000);
                }
            }
#pragma unroll
            for (int nt = 0; nt < 2; nt++)
#pragma unroll
                for (int mt = 0; mt < 2; mt++) {
                    aP[mt][nt] = __builtin_amdgcn_mfma_f32_32x32x16_bf16(pah[ks][mt], bf[nt], aP[mt][nt], 0, 0, 0);
                    aQ[mt][nt] = __builtin_amdgcn_mfma_f32_32x32x16_bf16(pah[ks][mt], isO ? nbf[nt] : bf[nt], aQ[mt][nt], 0, 0, 0);
                    if (isHi) {
                        aP[mt][nt] = __builtin_amdgcn_mfma_f32_32x32x16_bf16(pal[ks][mt], bf[nt], aP[mt][nt], 0, 0, 0);
                        aQ[mt][nt] = __builtin_amdgcn_mfma_f32_32x32x16_bf16(pal[ks][mt], isO ? nbf[nt] : bf[nt], aQ[mt][nt], 0, 0, 0);
                    }
                }
        }
        if (r < 3) SBAR;  // readers done before next round's DMA overwrites buf
    }
    // epilogue: bias + gelu on both halves, butterfly to E/O, split-store
#pragma unroll
    for (int mt = 0; mt < 2; mt++)
#pragma unroll
        for (int nt = 0; nt < 2; nt++)
#pragma unroll
            for (int reg = 0; reg < 16; reg++) {
                int roffs = (reg & 3) + 8 * (reg >> 2) + 4 * lh;
                float bias = pwb[l * CC + mt * 32 + roffs];
                float uu = aP[mt][nt][reg] + bias;
                float vv = aQ[mt][nt][reg] + bias;
                if (gel) {
                    uu = gelu_exact(uu);
                    vv = gelu_exact(vv);
                }
                float EE = uu + vv, OO = uu - vv;
                ushort h2, l2;
                size_t gg = (size_t)(row0 + wm + mt * 32 + roffs) * HS + n0 + wn + nt * 32 + l32;
                split2(EE, h2, l2);
                Eh[gg] = h2;
                El[gg] = l2;
                split2(OO, h2, l2);
                Oh[gg] = h2;
                Ol[gg] = l2;
            }
}

// ---------------- projection head (MFMA, register-transpose staging) --------
// Block: one (b, 64-position) tile. Fragment assembly happens in REGISTERS
// (round-3 bug: scalar LDS writes along the channel axis were a 16-way bank
// conflict, 69M conflict cycles). Each thread gathers the 8 channels of its
// fragment directly from global (lane = n/j -> 128/256B coalesced per
// instruction), then stores one b128 per fragment (lanes write consecutive
// 16B chunks = conflict-free).
// fc1 MFMA with W1 as "a" (j via regs) and X as "b" (n via lanes): fc2
// j-reduction = 15 in-register adds + one shfl_xor(32); out col = lane = n.
__global__ __launch_bounds__(256, 3) void head_kernel(
    const ushort* __restrict__ Eh, const ushort* __restrict__ El,
    const ushort* __restrict__ Oh, const ushort* __restrict__ Ol,
    const float* __restrict__ w1, const float* __restrict__ b1,
    const float* __restrict__ w2, const float* __restrict__ b2,
    float* __restrict__ out) {
    __shared__ __align__(16) ushort Xh[4096];  // [kg8][n64][8]  8 KB
    __shared__ __align__(16) ushort Xl[4096];
    __shared__ __align__(16) ushort Wh[8192];  // [kg8][j128][8] 16 KB
    __shared__ __align__(16) ushort Wl[8192];
    __shared__ float part[4][64];
    const int b = blockIdx.y;
    const int n0 = blockIdx.x * 64;
    const int t = threadIdx.x;
    const int lane = t & 63, w = t >> 6;
    const int l32 = lane & 31, lh = lane >> 5;
    const float sg = (n0 < HS) ? 0.5f : -0.5f;  // 0.5 folded into X
    const int nc = n0 & (HS - 1);
    // ---- stage X: wave w gathers channels [w*16, w*16+16) for n = lane.
    // Per-instruction: 64 lanes x 2B consecutive n = 128B coalesced.
    {
        const int n = lane;
        const size_t gx = (size_t)(b * CC + w * 16) * HS + nc + n;
        short8 fh[2], fl[2];
#pragma unroll
        for (int cc = 0; cc < 16; cc++) {
            size_t g = gx + (size_t)cc * HS;
            float e = b2f(Eh[g]) + b2f(El[g]);
            float o = b2f(Oh[g]) + b2f(Ol[g]);
            float x = 0.5f * e + sg * o;
            ushort hh, ll;
            split2(x, hh, ll);
            fh[cc >> 3][cc & 7] = (short)hh;
            fl[cc >> 3][cc & 7] = (short)ll;
        }
        const int kg0 = w * 2;
#pragma unroll
        for (int q = 0; q < 2; q++) {
            *(short8*)&Xh[((kg0 + q) * 64 + n) * 8] = fh[q];
            *(short8*)&Xl[((kg0 + q) * 64 + n) * 8] = fl[q];
        }
    }
    // ---- stage W1: thread handles j = t&127, c in [half*32, half*32+32).
    // Loads lane-consecutive j (256B/instruction); b128 fragment stores.
    {
        const int j = t & 127, half = t >> 7;
#pragma unroll
        for (int q = 0; q < 4; q++) {
            const int kg = half * 4 + q;
            short8 fh, fl;
#pragma unroll
            for (int e = 0; e < 8; e++) {
                int c = kg * 8 + e;
                ushort hh, ll;
                split2(w1[c * 128 + j], hh, ll);
                fh[e] = (short)hh;
                fl[e] = (short)ll;
            }
            *(short8*)&Wh[(kg * 128 + j) * 8] = fh;
            *(short8*)&Wl[(kg * 128 + j) * 8] = fl;
        }
    }
    __syncthreads();
    // ---- fc1 GEMM: wave w owns j-rows [w*32, w*32+32) (via regs), n via lanes
    f32x16 acc[2];
    acc[0] = (f32x16)0.f;
    acc[1] = (f32x16)0.f;
#pragma unroll
    for (int ks = 0; ks < 4; ks++) {
        const int kg = ks * 2 + lh;
        const int offa = (kg * 128 + w * 32 + l32) * 8;
        short8 awh = *(const short8*)&Wh[offa];
        short8 awl = *(const short8*)&Wl[offa];
#pragma unroll
        for (int nt = 0; nt < 2; nt++) {
            const int offb = (kg * 64 + nt * 32 + l32) * 8;
            short8 bxh = *(const short8*)&Xh[offb];
            short8 bxl = *(const short8*)&Xl[offb];
            acc[nt] = __builtin_amdgcn_mfma_f32_32x32x16_bf16(awh, bxh, acc[nt], 0, 0, 0);
            acc[nt] = __builtin_amdgcn_mfma_f32_32x32x16_bf16(awh, bxl, acc[nt], 0, 0, 0);
            acc[nt] = __builtin_amdgcn_mfma_f32_32x32x16_bf16(awl, bxh, acc[nt], 0, 0, 0);
        }
    }
    // ---- fc2 fused: bias + gelu + *w2[j]; reduce over j = regs + lh-swap
#pragma unroll
    for (int nt = 0; nt < 2; nt++) {
        float s = 0.f;
#pragma unroll
        for (int reg = 0; reg < 16; reg++) {
            const int j0 = w * 32 + (reg & 3) + 8 * (reg >> 2) + 4 * lh;
            s += gelu_exact(acc[nt][reg] + b1[j0]) * w2[j0];
        }
        s += __shfl_xor(s, 32);
        part[w][nt * 32 + l32] = s;  // both lh halves write identical value
    }
    __syncthreads();
    if (t < 64)
        out[b * SS + n0 + t] = part[0][t] + part[1][t] + part[2][t] + part[3][t] + b2[0];
}

extern "C" void kernel_launch(void* const* d_in, const int* in_sizes, int n_in,
                              void* d_out, int out_size, void* d_ws, size_t ws_size,
                              hipStream_t stream) {
    (void)in_sizes; (void)n_in; (void)out_size; (void)ws_size;
    const float* u = (const float*)d_in[0];
    const float* fc0_w = (const float*)d_in[1];
    const float* fc0_b = (const float*)d_in[2];
    const float* sw_r = (const float*)d_in[3];
    const float* sw_i = (const float*)d_in[4];
    const float* pw_w = (const float*)d_in[5];
    const float* pw_b = (const float*)d_in[6];
    const float* fc1_w = (const float*)d_in[7];
    const float* fc1_b = (const float*)d_in[8];
    const float* fc2_w = (const float*)d_in[9];
    const float* fc2_b = (const float*)d_in[10];
    float* out = (float*)d_out;

    // workspace layout (total = 167,772,160 B)
    char* ws = (char*)d_ws;
    ushort* Eh = (ushort*)ws;                  // [4096][4096]
    ushort* El = (ushort*)(ws + 33554432);
    ushort* Oh = (ushort*)(ws + 67108864);
    ushort* Ol = (ushort*)(ws + 100663296);
    ushort* t1h = (ushort*)(ws + 134217728);   // [512][4096]
    ushort* t1l = (ushort*)(ws + 138412032);
    ushort* t2h = (ushort*)(ws + 142606336);   // [4096][512]
    ushort* t2l = (ushort*)(ws + 146800640);
    ushort* omh = (ushort*)(ws + 150994944);   // [4096][512]
    ushort* oml = (ushort*)(ws + 155189248);
    float* Xf = (float*)(ws + 159383552);      // [4096][512] fp32

    build_T1p<<<dim3(KK2, HS / 256), 256, 0, stream>>>(t1h, t1l);
    build_T2r<<<dim3(HS, KK2 / 256), 256, 0, stream>>>(t2h, t2l);
    lift_kernel<<<dim3(HS / 256, CC, BB), 256, 0, stream>>>(u, fc0_w, fc0_b, Eh, El,
                                                            Oh, Ol);
    for (int l = 0; l < 4; l++) {
        hipMemsetAsync(Xf, 0, (size_t)HS * KK2 * sizeof(float), stream);
        dft_mfma<<<dim3(512), 256, 0, stream>>>(Eh, El, Oh, Ol, t1h, t1l, Xf);
        mode_mix<<<dim3(BB / 2, CC / 2), 256, 0, stream>>>(Xf, sw_r, sw_i, omh, oml, l);
        inv_mfma<<<dim3(HS / 128, 32), 256, 0, stream>>>(
            omh, oml, t2h, t2l, pw_w, pw_b, Eh, El, Oh, Ol, l, (l < 3) ? 1 : 0);
    }
    head_kernel<<<dim3(SS / 64, BB), 256, 0, stream>>>(Eh, El, Oh, Ol, fc1_w, fc1_b,
                                                       fc2_w, fc2_b, out);
}